// Round 16
// baseline (63.626 us; speedup 1.0000x reference)
//
#include <hip/hip_runtime.h>
#include <hip/hip_bf16.h>

// LocalFeatureAggregation: B=2, N=32768, K=16, CIN=8, COUT=64
// MFMA version 12 = round-14 (51.6 µs, best) + register-peak diet for 3 waves/SIMD:
//  (a) b2f loaded 1-fragment-per-t inside MLP2 (peak 4 regs, was 16 persistent);
//      b3f loaded 2-fragments-per-t inside ATT (peak 8, was 32 persistent).
//      ATT phase was the register peak (~170); now ~140 -> fits 512/3 cap.
//  (b) launch_bounds(64,3): 3 waves/SIMD target (round-9's spill was because
//      the peak stayed at ~170 under the same cap; (a) actually lowers it).
//  (c) prefetch issued right after h1 store (round 15's one good idea).
// LDS unchanged at 12800 B (round-15 lesson: LDS growth eats residency).
// Tripwire: WRITE_SIZE must stay 16384 KB (no scratch spill).
// Grid = 4096 blocks x 4 iters x 4 points; deferred pool epilogue.

typedef __attribute__((ext_vector_type(8))) short short8v;
typedef __attribute__((ext_vector_type(4))) float float4v;

#define BN_INV 0.9999950000374997f
#define LOG2E  1.4426950408889634f
#define NFRAG 23
#define NSCAL 24

// cheap float->bf16, round-half-up (1-ulp-on-ties vs RNE; inputs finite)
__device__ __forceinline__ ushort f2bf(float f) {
    return (ushort)((__float_as_uint(f) + 0x8000u) >> 16);
}
// pack two: low half = bf16(a), high half = bf16(b)
__device__ __forceinline__ uint pk2(float a, float b) {
    return __builtin_amdgcn_perm(__float_as_uint(b) + 0x8000u,
                                 __float_as_uint(a) + 0x8000u, 0x07060302u);
}
__device__ __forceinline__ ushort f2bf_rne(float f) {
    __hip_bfloat16 h = __float2bfloat16(f);
    return __builtin_bit_cast(ushort, h);
}
__device__ __forceinline__ float fexp2(float x) {
#if __has_builtin(__builtin_amdgcn_exp2f)
    return __builtin_amdgcn_exp2f(x);
#else
    return exp2f(x);
#endif
}

// ---- setup: pack per-lane MFMA B-fragments + scale/shift into d_ws ----
// layout: [NFRAG][64] x 16B fragments, then [NSCAL][64] x f32.
// frag order: 0 b1f0, 1 b1f1, 2-5 b2f[t], 6-13 b3f[2t+h], 14-21 pbf[2t+h],
//             22 w2f (LSE2 A-operand, rows prescaled by g2*BN_INV, Q!=0 -> 0).
// b2f k-columns permuted by ch2(p) = (p>>1) + 16*(p&1)  (X2 pair layout);
// b3f/pbf k-columns permuted by ch3(p) = 16*(p&3) + (p>>2) (X3/PL quad layout);
// b3f additionally scaled by log2(e) for the exp2 softmax.
// scalars: 0-19 as before; 20-23: b2lse[4Q+q] (LSE2 bias per-lane).
__global__ __launch_bounds__(256)
void lfa_pack(const float* __restrict__ wm1, const float* __restrict__ wm2,
              const float* __restrict__ watt, const float* __restrict__ wp,
              const float* __restrict__ gm1, const float* __restrict__ bm1,
              const float* __restrict__ gm2, const float* __restrict__ bm2,
              const float* __restrict__ gp,  const float* __restrict__ bp,
              const float* __restrict__ w2,  const float* __restrict__ g2,
              const float* __restrict__ b2,
              ushort* __restrict__ ws)
{
    const int t = blockIdx.x * 256 + threadIdx.x;
    if (t < NFRAG * 64) {
        const int f = t >> 6, l = t & 63, r = l & 15, Q = l >> 4;
        short8v v;
        #pragma unroll
        for (int j = 0; j < 8; ++j) {
            const int k = 8 * Q + j;
            float x;
            if (f == 0)      x = (k < 24) ? wm1[r * 24 + k] : 0.f;
            else if (f == 1) x = (k < 24) ? wm1[(16 + r) * 24 + k] : 0.f;
            else if (f < 6)  { int tt = f - 2;
                               int c = (k >> 1) + 16 * (k & 1);
                               x = wm2[(16 * tt + r) * 32 + c]; }
            else if (f < 14) { int i = f - 6,  tt = i >> 1, h = i & 1;
                               int p = 32 * h + k;
                               int c = 16 * (p & 3) + (p >> 2);
                               x = watt[(16 * tt + r) * 64 + c] * LOG2E; }
            else if (f < 22) { int i = f - 14, tt = i >> 1, h = i & 1;
                               int p = 32 * h + k;
                               int c = 16 * (p & 3) + (p >> 2);
                               x = wp[(16 * tt + r) * 64 + c]; }
            else             { x = (k < 8) ? w2[r * 8 + k] * (g2[r] * BN_INV) : 0.f; }
            v[j] = (short)f2bf_rne(x);
        }
        ((short8v*)ws)[t] = v;
    } else if (t < NFRAG * 64 + NSCAL * 64) {
        const int i = t - NFRAG * 64;
        const int fld = i >> 6, l = i & 63, r = l & 15, Q = l >> 4;
        float x;
        if (fld == 0)      x = gm1[r] * BN_INV;
        else if (fld == 1) x = bm1[r];
        else if (fld == 2) x = gm1[16 + r] * BN_INV;
        else if (fld == 3) x = bm1[16 + r];
        else if (fld < 8)  x = gm2[16 * (fld - 4) + r] * BN_INV;
        else if (fld < 12) x = bm2[16 * (fld - 8) + r];
        else if (fld < 16) x = gp[16 * (fld - 12) + r] * BN_INV;
        else if (fld < 20) x = bp[16 * (fld - 16) + r];
        else               x = b2[4 * Q + (fld - 20)];
        ((float*)(ws + NFRAG * 64 * 8))[i] = x;
    }
}

__global__ __launch_bounds__(64, 3)
void lfa_kernel(const float* __restrict__ coords,
                const float* __restrict__ feats,
                const int*   __restrict__ nidx,
                const float* __restrict__ w1, const float* __restrict__ g1, const float* __restrict__ b1,
                const ushort* __restrict__ fw,
                float* __restrict__ out)
{
    // one wave per block: X1 4pt x 16 rows x 40 ushorts (pt stride 648)
    //                     sX2: Xh transpose buf (LSE) / X2 pair tiles / X3B
    //                     X3A 16 x 72 ; PL 16 rows x 72 (all 16 block points)
    __shared__ __align__(16) ushort sX1[2592];
    __shared__ __align__(16) ushort sX2[1280];
    __shared__ __align__(16) ushort sX3[1152];
    __shared__ __align__(16) ushort sPL[1152];   // 12352 B total

    const int l   = threadIdx.x & 63;
    const int r   = l & 15;
    const int Q   = l >> 4;
    const int ptb = blockIdx.x * 16;

    // ---- persistent fragments (b1/w2f only; b2f/b3f are per-use transient,
    //      pool fragments loaded at the epilogue) ----
    const short8v* FR = (const short8v*)fw;
    const float*   SC = (const float*)(fw + NFRAG * 64 * 8);
    const short8v b1f0 = FR[0 * 64 + l];
    const short8v b1f1 = FR[1 * 64 + l];
    const short8v w2f  = FR[22 * 64 + l];

    const float sm1a = SC[0 * 64 + l], tm1a = SC[1 * 64 + l];
    const float sm1b = SC[2 * 64 + l], tm1b = SC[3 * 64 + l];
    float sm2[4], tm2[4], t2l[4];
    #pragma unroll
    for (int t = 0; t < 4; ++t) {
        sm2[t] = SC[(4 + t) * 64 + l];  tm2[t] = SC[(8 + t) * 64 + l];
        t2l[t] = SC[(20 + t) * 64 + l];
    }

    ushort* X1  = sX1;
    ushort* X2A = sX2;
    ushort* X2B = X2A + 640;
    ushort* X3A = sX3;
    ushort* X3B = sX2;            // 16 x 72 = 1152 <= 1280, aliases X2A/X2B
    ushort* Xh  = sX2;            // 80 rows x 8 ushorts (LSE transpose buf)

    // ---- prologue gather (it = 0): exposed once per block ----
    float cx, cy, cz, nx, ny, nz;
    float4 f0v, f1v;
    {
        const int pt0n = ptb;
        const int pt   = pt0n + Q;
        const int nb   = nidx[pt0n * 16 + l];
        const int bb   = pt >> 15;
        const int nbr  = (bb << 15) + nb;
        cx = coords[pt * 3 + 0];  cy = coords[pt * 3 + 1];  cz = coords[pt * 3 + 2];
        nx = coords[nbr * 3 + 0]; ny = coords[nbr * 3 + 1]; nz = coords[nbr * 3 + 2];
        const float4* fp4 = (const float4*)(feats + nbr * 8);
        f0v = fp4[0]; f1v = fp4[1];
    }

    const float4v z0 = {0.f, 0.f, 0.f, 0.f};

    #pragma unroll 1
    for (int it = 0; it < 4; ++it) {
        // ===== LSE phase: lane = (point Q, nbr r); layer 2 via swapped MFMA =====
        {
            // zero Xh pad rows 64..79 (clobbered by X3B last iter)
            *(uint*)&Xh[512 + 2 * l] = 0u;

            const float rx = nx - cx;
            const float ry = ny - cy;
            const float rz = nz - cz;
            const float dd = sqrtf(rx * rx + ry * ry + rz * rz);
            float e4[4] = {rx, ry, rz, dd};

            // nf -> X1 row slots 0..7, zero pad 24..31
            uint4* row = (uint4*)&X1[Q * 648 + r * 40];
            row[0] = make_uint4(pk2(f0v.x, f0v.y), pk2(f0v.z, f0v.w),
                                pk2(f1v.x, f1v.y), pk2(f1v.z, f1v.w));
            row[3] = make_uint4(0u, 0u, 0u, 0u);

            float h1[8];
            #pragma unroll
            for (int o = 0; o < 8; ++o) {
                float a = 0.f;
                #pragma unroll
                for (int i = 0; i < 4; ++i) a = fmaf(w1[o * 4 + i], e4[i], a);
                h1[o] = fmaxf(fmaf(a, g1[o] * BN_INV, b1[o]), 0.f);
            }
            // h1 -> Xh[l] (row l = this lane's (pt,k) row)
            *(uint4*)&Xh[l * 8] = make_uint4(pk2(h1[0], h1[1]), pk2(h1[2], h1[3]),
                                             pk2(h1[4], h1[5]), pk2(h1[6], h1[7]));

            // ===== prefetch gather for it+1 (all inputs consumed above) =====
            if (it < 3) {
                const int pt0n = ptb + (it + 1) * 4;
                const int pt   = pt0n + Q;
                const int nb   = nidx[pt0n * 16 + l];
                const int bb   = pt >> 15;
                const int nbr  = (bb << 15) + nb;
                cx = coords[pt * 3 + 0];  cy = coords[pt * 3 + 1];  cz = coords[pt * 3 + 2];
                nx = coords[nbr * 3 + 0]; ny = coords[nbr * 3 + 1]; nz = coords[nbr * 3 + 2];
                const float4* fp4 = (const float4*)(feats + nbr * 8);
                f0v = fp4[0]; f1v = fp4[1];
            }

            // per point t: one swapped MFMA -> enc16 into X1
            #pragma unroll
            for (int t = 0; t < 4; ++t) {
                const int rowi = (Q == 0) ? (16 * t + r) : (64 + r);
                const short8v bh = *(const short8v*)&Xh[rowi * 8];
                const float4v de = __builtin_amdgcn_mfma_f32_16x16x32_bf16(w2f, bh, z0, 0, 0, 0);
                const float v0 = fmaxf(de[0] + t2l[0], 0.f);
                const float v1 = fmaxf(de[1] + t2l[1], 0.f);
                const float v2 = fmaxf(de[2] + t2l[2], 0.f);
                const float v3 = fmaxf(de[3] + t2l[3], 0.f);
                *(uint2*)&X1[t * 648 + r * 40 + 8 + 4 * Q] =
                    make_uint2(pk2(v0, v1), pk2(v2, v3));
            }
        }

        // ===== paired per-point MFMA chains (points 2pp, 2pp+1) =====
        __builtin_amdgcn_s_setprio(1);
        #pragma unroll 1
        for (int pp = 0; pp < 2; ++pp) {
            int zi = 0;
            asm volatile("" : "+v"(zi));   // opaque index: keep frag loads per-use

            ushort* X1A = X1 + (2 * pp) * 648;
            ushort* X1B = X1A + 648;
            const short8v a1A = *(const short8v*)&X1A[r * 40 + Q * 8];
            const short8v a1B = *(const short8v*)&X1B[r * 40 + Q * 8];
            const float4v d1aA = __builtin_amdgcn_mfma_f32_16x16x32_bf16(a1A, b1f0, z0, 0, 0, 0);
            const float4v d1bA = __builtin_amdgcn_mfma_f32_16x16x32_bf16(a1A, b1f1, z0, 0, 0, 0);
            const float4v d1aB = __builtin_amdgcn_mfma_f32_16x16x32_bf16(a1B, b1f0, z0, 0, 0, 0);
            const float4v d1bB = __builtin_amdgcn_mfma_f32_16x16x32_bf16(a1B, b1f1, z0, 0, 0, 0);
            // X2: paired-channel b32 writes (pos 2o <-> ch o, 2o+1 <-> ch 16+o)
            #pragma unroll
            for (int q = 0; q < 4; ++q) {
                const float vaA = fmaxf(fmaf(d1aA[q], sm1a, tm1a), 0.f);
                const float vbA = fmaxf(fmaf(d1bA[q], sm1b, tm1b), 0.f);
                const float vaB = fmaxf(fmaf(d1aB[q], sm1a, tm1a), 0.f);
                const float vbB = fmaxf(fmaf(d1bB[q], sm1b, tm1b), 0.f);
                *(uint*)&X2A[(4 * Q + q) * 40 + 2 * r] = pk2(vaA, vbA);
                *(uint*)&X2B[(4 * Q + q) * 40 + 2 * r] = pk2(vaB, vbB);
            }
            const short8v a2A = *(const short8v*)&X2A[r * 40 + Q * 8];
            const short8v a2B = *(const short8v*)&X2B[r * 40 + Q * 8];
            // MLP2: b2f loaded 1-per-t (transient, peak 4 regs)
            float xrA[4][4], xrB[4][4];
            #pragma unroll
            for (int t = 0; t < 4; ++t) {
                const short8v bw = FR[(2 + t) * 64 + l + zi];
                const float4v d2A = __builtin_amdgcn_mfma_f32_16x16x32_bf16(a2A, bw, z0, 0, 0, 0);
                const float4v d2B = __builtin_amdgcn_mfma_f32_16x16x32_bf16(a2B, bw, z0, 0, 0, 0);
                #pragma unroll
                for (int q = 0; q < 4; ++q) {
                    xrA[t][q] = fmaxf(fmaf(d2A[q], sm2[t], tm2[t]), 0.f);
                    xrB[t][q] = fmaxf(fmaf(d2B[q], sm2[t], tm2[t]), 0.f);
                }
            }

            // X3: quad-channel b64 writes (pos 4r+t <-> ch 16t+r)
            #pragma unroll
            for (int q = 0; q < 4; ++q) {
                *(uint2*)&X3A[(4 * Q + q) * 72 + 4 * r] =
                    make_uint2(pk2(xrA[0][q], xrA[1][q]), pk2(xrA[2][q], xrA[3][q]));
                *(uint2*)&X3B[(4 * Q + q) * 72 + 4 * r] =
                    make_uint2(pk2(xrB[0][q], xrB[1][q]), pk2(xrB[2][q], xrB[3][q]));
            }
            const short8v a3lA = *(const short8v*)&X3A[r * 72 + Q * 8];
            const short8v a3hA = *(const short8v*)&X3A[r * 72 + 32 + Q * 8];
            const short8v a3lB = *(const short8v*)&X3B[r * 72 + Q * 8];
            const short8v a3hB = *(const short8v*)&X3B[r * 72 + 32 + Q * 8];

            // ---- interleaved ATT + softmax; b3f loaded 2-per-t (peak 8 regs) ----
            float seA[4], snA[4], seB[4], snB[4];
            #pragma unroll
            for (int t = 0; t < 4; ++t) {
                const short8v bl = FR[(6 + 2 * t) * 64 + l + zi];
                const short8v bh = FR[(7 + 2 * t) * 64 + l + zi];
                float4v sA = __builtin_amdgcn_mfma_f32_16x16x32_bf16(a3lA, bl, z0, 0, 0, 0);
                sA         = __builtin_amdgcn_mfma_f32_16x16x32_bf16(a3hA, bh, sA, 0, 0, 0);
                float4v sB = __builtin_amdgcn_mfma_f32_16x16x32_bf16(a3lB, bl, z0, 0, 0, 0);
                sB         = __builtin_amdgcn_mfma_f32_16x16x32_bf16(a3hB, bh, sB, 0, 0, 0);
                float e0A = fexp2(sA[0]), e1A = fexp2(sA[1]);
                float e2A = fexp2(sA[2]), e3A = fexp2(sA[3]);
                float e0B = fexp2(sB[0]), e1B = fexp2(sB[1]);
                float e2B = fexp2(sB[2]), e3B = fexp2(sB[3]);
                seA[t] = (e0A + e1A) + (e2A + e3A);
                snA[t] = fmaf(e0A, xrA[t][0], e1A * xrA[t][1]) + fmaf(e2A, xrA[t][2], e3A * xrA[t][3]);
                seB[t] = (e0B + e1B) + (e2B + e3B);
                snB[t] = fmaf(e0B, xrB[t][0], e1B * xrB[t][1]) + fmaf(e2B, xrB[t][2], e3B * xrB[t][3]);
            }
            #pragma unroll
            for (int t = 0; t < 4; ++t) {
                seA[t] += __shfl_xor(seA[t], 16, 64);
                snA[t] += __shfl_xor(snA[t], 16, 64);
                seB[t] += __shfl_xor(seB[t], 16, 64);
                snB[t] += __shfl_xor(snB[t], 16, 64);
                seA[t] += __shfl_xor(seA[t], 32, 64);
                snA[t] += __shfl_xor(snA[t], 32, 64);
                seB[t] += __shfl_xor(seB[t], 32, 64);
                snB[t] += __shfl_xor(snB[t], 32, 64);
            }
            // all-lane tail: lane handles t=Q, channel 16Q+r -> PL pos 4r+Q
            {
                const float snqA = (Q == 0) ? snA[0] : (Q == 1) ? snA[1] : (Q == 2) ? snA[2] : snA[3];
                const float seqA = (Q == 0) ? seA[0] : (Q == 1) ? seA[1] : (Q == 2) ? seA[2] : seA[3];
                const float snqB = (Q == 0) ? snB[0] : (Q == 1) ? snB[1] : (Q == 2) ? snB[2] : snB[3];
                const float seqB = (Q == 0) ? seB[0] : (Q == 1) ? seB[1] : (Q == 2) ? seB[2] : seB[3];
                sPL[(4 * it + 2 * pp) * 72 + 4 * r + Q]     = f2bf(__fdividef(snqA, seqA));
                sPL[(4 * it + 2 * pp + 1) * 72 + 4 * r + Q] = f2bf(__fdividef(snqB, seqB));
            }
        }
        __builtin_amdgcn_s_setprio(0);
    }

    // ===== ONE pool MFMA epilogue for all 16 block points (all lanes valid) =====
    short8v pbf[8];
    #pragma unroll
    for (int i = 0; i < 8; ++i) pbf[i] = FR[(14 + i) * 64 + l];
    float spv[4], tpv[4];
    #pragma unroll
    for (int t = 0; t < 4; ++t) {
        spv[t] = SC[(12 + t) * 64 + l]; tpv[t] = SC[(16 + t) * 64 + l];
    }
    const short8v apl0 = *(const short8v*)&sPL[r * 72 + Q * 8];
    const short8v apl1 = *(const short8v*)&sPL[r * 72 + 32 + Q * 8];
    float4v dp[4];
    #pragma unroll
    for (int t = 0; t < 4; ++t) {
        float4v d = __builtin_amdgcn_mfma_f32_16x16x32_bf16(apl0, pbf[t * 2],     z0, 0, 0, 0);
        d         = __builtin_amdgcn_mfma_f32_16x16x32_bf16(apl1, pbf[t * 2 + 1], d,  0, 0, 0);
        dp[t] = d;
    }
    // D: row = 4Q+q = block point, col = 16t+r = output channel -> dense stores
    #pragma unroll
    for (int q = 0; q < 4; ++q)
        #pragma unroll
        for (int t = 0; t < 4; ++t)
            out[(ptb + 4 * Q + q) * 64 + 16 * t + r] =
                fmaxf(fmaf(dp[t][q], spv[t], tpv[t]), 0.f);
}

extern "C" void kernel_launch(void* const* d_in, const int* in_sizes, int n_in,
                              void* d_out, int out_size, void* d_ws, size_t ws_size,
                              hipStream_t stream) {
    (void)in_sizes; (void)n_in; (void)ws_size; (void)out_size;
    const float* coords = (const float*)d_in[0];
    const float* feats  = (const float*)d_in[1];
    const int*   nidx   = (const int*)  d_in[2];
    const float* w1  = (const float*)d_in[3];
    const float* g1  = (const float*)d_in[4];
    const float* b1  = (const float*)d_in[5];
    const float* w2  = (const float*)d_in[6];
    const float* g2  = (const float*)d_in[7];
    const float* b2  = (const float*)d_in[8];
    const float* wm1 = (const float*)d_in[9];
    const float* gm1 = (const float*)d_in[10];
    const float* bm1 = (const float*)d_in[11];
    const float* wm2 = (const float*)d_in[12];
    const float* gm2 = (const float*)d_in[13];
    const float* bm2 = (const float*)d_in[14];
    const float* watt = (const float*)d_in[15];
    const float* wp  = (const float*)d_in[16];
    const float* gp  = (const float*)d_in[17];
    const float* bp  = (const float*)d_in[18];
    float* out = (float*)d_out;
    ushort* ws = (ushort*)d_ws;

    lfa_pack<<<dim3(12), dim3(256), 0, stream>>>(wm1, wm2, watt, wp,
                                                 gm1, bm1, gm2, bm2, gp, bp,
                                                 w2, g2, b2, ws);
    lfa_kernel<<<dim3(4096), dim3(64), 0, stream>>>(coords, feats, nidx,
                                                    w1, g1, b1, ws, out);
}

// Round 17
// 51.492 us; speedup vs baseline: 1.2357x; 1.2357x over previous
//
#include <hip/hip_runtime.h>
#include <hip/hip_bf16.h>

// LocalFeatureAggregation: B=2, N=32768, K=16, CIN=8, COUT=64
// MFMA version 10 (round-14, PROVEN BEST 51.6 µs) — reverted verbatim.
// Post-r14 probes all regressed: r15 (de-alias+unroll: LDS 23KB cost a
// resident wave, 62 µs), r16 (transient frags + 3 waves/SIMD: in-chain L2
// latency > occupancy gain, 63.6 µs). This structure is the measured local
// optimum: persistent fragments, 12.8 KB LDS, paired A/B chains, setprio,
// LSE2-as-swapped-MFMA, channel-permuted LDS bridges, exp2 softmax,
// deferred all-lane pool epilogue.
// Grid = 4096 blocks x 4 iters x 4 points.

typedef __attribute__((ext_vector_type(8))) short short8v;
typedef __attribute__((ext_vector_type(4))) float float4v;

#define BN_INV 0.9999950000374997f
#define LOG2E  1.4426950408889634f
#define NFRAG 23
#define NSCAL 24

// cheap float->bf16, round-half-up (1-ulp-on-ties vs RNE; inputs finite)
__device__ __forceinline__ ushort f2bf(float f) {
    return (ushort)((__float_as_uint(f) + 0x8000u) >> 16);
}
// pack two: low half = bf16(a), high half = bf16(b)
__device__ __forceinline__ uint pk2(float a, float b) {
    return __builtin_amdgcn_perm(__float_as_uint(b) + 0x8000u,
                                 __float_as_uint(a) + 0x8000u, 0x07060302u);
}
__device__ __forceinline__ ushort f2bf_rne(float f) {
    __hip_bfloat16 h = __float2bfloat16(f);
    return __builtin_bit_cast(ushort, h);
}
__device__ __forceinline__ float fexp2(float x) {
#if __has_builtin(__builtin_amdgcn_exp2f)
    return __builtin_amdgcn_exp2f(x);
#else
    return exp2f(x);
#endif
}

// ---- setup: pack per-lane MFMA B-fragments + scale/shift into d_ws ----
// layout: [NFRAG][64] x 16B fragments, then [NSCAL][64] x f32.
// frag order: 0 b1f0, 1 b1f1, 2-5 b2f[t], 6-13 b3f[2t+h], 14-21 pbf[2t+h],
//             22 w2f (LSE2 A-operand, rows prescaled by g2*BN_INV, Q!=0 -> 0).
// b2f k-columns permuted by ch2(p) = (p>>1) + 16*(p&1)  (X2 pair layout);
// b3f/pbf k-columns permuted by ch3(p) = 16*(p&3) + (p>>2) (X3/PL quad layout);
// b3f additionally scaled by log2(e) for the exp2 softmax.
// scalars: 0-19 as before; 20-23: b2lse[4Q+q] (LSE2 bias per-lane).
__global__ __launch_bounds__(256)
void lfa_pack(const float* __restrict__ wm1, const float* __restrict__ wm2,
              const float* __restrict__ watt, const float* __restrict__ wp,
              const float* __restrict__ gm1, const float* __restrict__ bm1,
              const float* __restrict__ gm2, const float* __restrict__ bm2,
              const float* __restrict__ gp,  const float* __restrict__ bp,
              const float* __restrict__ w2,  const float* __restrict__ g2,
              const float* __restrict__ b2,
              ushort* __restrict__ ws)
{
    const int t = blockIdx.x * 256 + threadIdx.x;
    if (t < NFRAG * 64) {
        const int f = t >> 6, l = t & 63, r = l & 15, Q = l >> 4;
        short8v v;
        #pragma unroll
        for (int j = 0; j < 8; ++j) {
            const int k = 8 * Q + j;
            float x;
            if (f == 0)      x = (k < 24) ? wm1[r * 24 + k] : 0.f;
            else if (f == 1) x = (k < 24) ? wm1[(16 + r) * 24 + k] : 0.f;
            else if (f < 6)  { int tt = f - 2;
                               int c = (k >> 1) + 16 * (k & 1);
                               x = wm2[(16 * tt + r) * 32 + c]; }
            else if (f < 14) { int i = f - 6,  tt = i >> 1, h = i & 1;
                               int p = 32 * h + k;
                               int c = 16 * (p & 3) + (p >> 2);
                               x = watt[(16 * tt + r) * 64 + c] * LOG2E; }
            else if (f < 22) { int i = f - 14, tt = i >> 1, h = i & 1;
                               int p = 32 * h + k;
                               int c = 16 * (p & 3) + (p >> 2);
                               x = wp[(16 * tt + r) * 64 + c]; }
            else             { x = (k < 8) ? w2[r * 8 + k] * (g2[r] * BN_INV) : 0.f; }
            v[j] = (short)f2bf_rne(x);
        }
        ((short8v*)ws)[t] = v;
    } else if (t < NFRAG * 64 + NSCAL * 64) {
        const int i = t - NFRAG * 64;
        const int fld = i >> 6, l = i & 63, r = l & 15, Q = l >> 4;
        float x;
        if (fld == 0)      x = gm1[r] * BN_INV;
        else if (fld == 1) x = bm1[r];
        else if (fld == 2) x = gm1[16 + r] * BN_INV;
        else if (fld == 3) x = bm1[16 + r];
        else if (fld < 8)  x = gm2[16 * (fld - 4) + r] * BN_INV;
        else if (fld < 12) x = bm2[16 * (fld - 8) + r];
        else if (fld < 16) x = gp[16 * (fld - 12) + r] * BN_INV;
        else if (fld < 20) x = bp[16 * (fld - 16) + r];
        else               x = b2[4 * Q + (fld - 20)];
        ((float*)(ws + NFRAG * 64 * 8))[i] = x;
    }
}

__global__ __launch_bounds__(64, 2)
void lfa_kernel(const float* __restrict__ coords,
                const float* __restrict__ feats,
                const int*   __restrict__ nidx,
                const float* __restrict__ w1, const float* __restrict__ g1, const float* __restrict__ b1,
                const ushort* __restrict__ fw,
                float* __restrict__ out)
{
    // one wave per block: X1 4pt x 16 rows x 40 ushorts (pt stride 648)
    //                     sX2: Xh transpose buf (LSE) / X2 pair tiles / X3B
    //                     X3A 16 x 72 ; PL 16 rows x 72 (all 16 block points)
    __shared__ __align__(16) ushort sX1[2592];
    __shared__ __align__(16) ushort sX2[1280];
    __shared__ __align__(16) ushort sX3[1152];
    __shared__ __align__(16) ushort sPL[1152];   // 12352 B total

    const int l   = threadIdx.x & 63;
    const int r   = l & 15;
    const int Q   = l >> 4;
    const int ptb = blockIdx.x * 16;

    // ---- persistent fragments (b1/b2/b3/w2f; pool stuff loaded at epilogue) ----
    const short8v* FR = (const short8v*)fw;
    const float*   SC = (const float*)(fw + NFRAG * 64 * 8);
    const short8v b1f0 = FR[0 * 64 + l];
    const short8v b1f1 = FR[1 * 64 + l];
    const short8v w2f  = FR[22 * 64 + l];
    short8v b2f[4], b3f[8];
    #pragma unroll
    for (int t = 0; t < 4; ++t) b2f[t] = FR[(2 + t) * 64 + l];
    #pragma unroll
    for (int i = 0; i < 8; ++i) b3f[i] = FR[(6 + i) * 64 + l];

    const float sm1a = SC[0 * 64 + l], tm1a = SC[1 * 64 + l];
    const float sm1b = SC[2 * 64 + l], tm1b = SC[3 * 64 + l];
    float sm2[4], tm2[4], t2l[4];
    #pragma unroll
    for (int t = 0; t < 4; ++t) {
        sm2[t] = SC[(4 + t) * 64 + l];  tm2[t] = SC[(8 + t) * 64 + l];
        t2l[t] = SC[(20 + t) * 64 + l];
    }

    ushort* X1  = sX1;
    ushort* X2A = sX2;
    ushort* X2B = X2A + 640;
    ushort* X3A = sX3;
    ushort* X3B = sX2;            // 16 x 72 = 1152 <= 1280, aliases X2A/X2B
    ushort* Xh  = sX2;            // 80 rows x 8 ushorts (LSE transpose buf)

    // ---- prologue gather (it = 0): exposed once per block ----
    float cx, cy, cz, nx, ny, nz;
    float4 f0v, f1v;
    {
        const int pt0n = ptb;
        const int pt   = pt0n + Q;
        const int nb   = nidx[pt0n * 16 + l];
        const int bb   = pt >> 15;
        const int nbr  = (bb << 15) + nb;
        cx = coords[pt * 3 + 0];  cy = coords[pt * 3 + 1];  cz = coords[pt * 3 + 2];
        nx = coords[nbr * 3 + 0]; ny = coords[nbr * 3 + 1]; nz = coords[nbr * 3 + 2];
        const float4* fp4 = (const float4*)(feats + nbr * 8);
        f0v = fp4[0]; f1v = fp4[1];
    }

    const float4v z0 = {0.f, 0.f, 0.f, 0.f};

    #pragma unroll 1
    for (int it = 0; it < 4; ++it) {
        // ===== LSE phase: lane = (point Q, nbr r); layer 2 via swapped MFMA =====
        {
            // zero Xh pad rows 64..79 (clobbered by X3B last iter)
            *(uint*)&Xh[512 + 2 * l] = 0u;

            const float rx = nx - cx;
            const float ry = ny - cy;
            const float rz = nz - cz;
            const float dd = sqrtf(rx * rx + ry * ry + rz * rz);
            float e4[4] = {rx, ry, rz, dd};

            // nf -> X1 row slots 0..7, zero pad 24..31
            uint4* row = (uint4*)&X1[Q * 648 + r * 40];
            row[0] = make_uint4(pk2(f0v.x, f0v.y), pk2(f0v.z, f0v.w),
                                pk2(f1v.x, f1v.y), pk2(f1v.z, f1v.w));
            row[3] = make_uint4(0u, 0u, 0u, 0u);

            float h1[8];
            #pragma unroll
            for (int o = 0; o < 8; ++o) {
                float a = 0.f;
                #pragma unroll
                for (int i = 0; i < 4; ++i) a = fmaf(w1[o * 4 + i], e4[i], a);
                h1[o] = fmaxf(fmaf(a, g1[o] * BN_INV, b1[o]), 0.f);
            }
            // h1 -> Xh[l] (row l = this lane's (pt,k) row)
            *(uint4*)&Xh[l * 8] = make_uint4(pk2(h1[0], h1[1]), pk2(h1[2], h1[3]),
                                             pk2(h1[4], h1[5]), pk2(h1[6], h1[7]));
            // per point t: one swapped MFMA -> enc16 into X1
            #pragma unroll
            for (int t = 0; t < 4; ++t) {
                const int rowi = (Q == 0) ? (16 * t + r) : (64 + r);
                const short8v bh = *(const short8v*)&Xh[rowi * 8];
                const float4v de = __builtin_amdgcn_mfma_f32_16x16x32_bf16(w2f, bh, z0, 0, 0, 0);
                const float v0 = fmaxf(de[0] + t2l[0], 0.f);
                const float v1 = fmaxf(de[1] + t2l[1], 0.f);
                const float v2 = fmaxf(de[2] + t2l[2], 0.f);
                const float v3 = fmaxf(de[3] + t2l[3], 0.f);
                *(uint2*)&X1[t * 648 + r * 40 + 8 + 4 * Q] =
                    make_uint2(pk2(v0, v1), pk2(v2, v3));
            }
        }

        // ===== prefetch gather for it+1 (latency hidden under pair phase) =====
        if (it < 3) {
            const int pt0n = ptb + (it + 1) * 4;
            const int pt   = pt0n + Q;
            const int nb   = nidx[pt0n * 16 + l];
            const int bb   = pt >> 15;
            const int nbr  = (bb << 15) + nb;
            cx = coords[pt * 3 + 0];  cy = coords[pt * 3 + 1];  cz = coords[pt * 3 + 2];
            nx = coords[nbr * 3 + 0]; ny = coords[nbr * 3 + 1]; nz = coords[nbr * 3 + 2];
            const float4* fp4 = (const float4*)(feats + nbr * 8);
            f0v = fp4[0]; f1v = fp4[1];
        }

        // ===== paired per-point MFMA chains (points 2pp, 2pp+1) =====
        __builtin_amdgcn_s_setprio(1);
        #pragma unroll 1
        for (int pp = 0; pp < 2; ++pp) {
            ushort* X1A = X1 + (2 * pp) * 648;
            ushort* X1B = X1A + 648;
            const short8v a1A = *(const short8v*)&X1A[r * 40 + Q * 8];
            const short8v a1B = *(const short8v*)&X1B[r * 40 + Q * 8];
            const float4v d1aA = __builtin_amdgcn_mfma_f32_16x16x32_bf16(a1A, b1f0, z0, 0, 0, 0);
            const float4v d1bA = __builtin_amdgcn_mfma_f32_16x16x32_bf16(a1A, b1f1, z0, 0, 0, 0);
            const float4v d1aB = __builtin_amdgcn_mfma_f32_16x16x32_bf16(a1B, b1f0, z0, 0, 0, 0);
            const float4v d1bB = __builtin_amdgcn_mfma_f32_16x16x32_bf16(a1B, b1f1, z0, 0, 0, 0);
            // X2: paired-channel b32 writes (pos 2o <-> ch o, 2o+1 <-> ch 16+o)
            #pragma unroll
            for (int q = 0; q < 4; ++q) {
                const float vaA = fmaxf(fmaf(d1aA[q], sm1a, tm1a), 0.f);
                const float vbA = fmaxf(fmaf(d1bA[q], sm1b, tm1b), 0.f);
                const float vaB = fmaxf(fmaf(d1aB[q], sm1a, tm1a), 0.f);
                const float vbB = fmaxf(fmaf(d1bB[q], sm1b, tm1b), 0.f);
                *(uint*)&X2A[(4 * Q + q) * 40 + 2 * r] = pk2(vaA, vbA);
                *(uint*)&X2B[(4 * Q + q) * 40 + 2 * r] = pk2(vaB, vbB);
            }
            const short8v a2A = *(const short8v*)&X2A[r * 40 + Q * 8];
            const short8v a2B = *(const short8v*)&X2B[r * 40 + Q * 8];
            float4v d2A[4], d2B[4];
            #pragma unroll
            for (int t = 0; t < 4; ++t) {
                d2A[t] = __builtin_amdgcn_mfma_f32_16x16x32_bf16(a2A, b2f[t], z0, 0, 0, 0);
                d2B[t] = __builtin_amdgcn_mfma_f32_16x16x32_bf16(a2B, b2f[t], z0, 0, 0, 0);
            }
            float xrA[4][4], xrB[4][4];
            #pragma unroll
            for (int t = 0; t < 4; ++t)
                #pragma unroll
                for (int q = 0; q < 4; ++q) {
                    xrA[t][q] = fmaxf(fmaf(d2A[t][q], sm2[t], tm2[t]), 0.f);
                    xrB[t][q] = fmaxf(fmaf(d2B[t][q], sm2[t], tm2[t]), 0.f);
                }

            // X3: quad-channel b64 writes (pos 4r+t <-> ch 16t+r)
            #pragma unroll
            for (int q = 0; q < 4; ++q) {
                *(uint2*)&X3A[(4 * Q + q) * 72 + 4 * r] =
                    make_uint2(pk2(xrA[0][q], xrA[1][q]), pk2(xrA[2][q], xrA[3][q]));
                *(uint2*)&X3B[(4 * Q + q) * 72 + 4 * r] =
                    make_uint2(pk2(xrB[0][q], xrB[1][q]), pk2(xrB[2][q], xrB[3][q]));
            }
            const short8v a3lA = *(const short8v*)&X3A[r * 72 + Q * 8];
            const short8v a3hA = *(const short8v*)&X3A[r * 72 + 32 + Q * 8];
            const short8v a3lB = *(const short8v*)&X3B[r * 72 + Q * 8];
            const short8v a3hB = *(const short8v*)&X3B[r * 72 + 32 + Q * 8];

            // ---- interleaved ATT + softmax (scores prescaled by log2e) ----
            float seA[4], snA[4], seB[4], snB[4];
            #pragma unroll
            for (int t = 0; t < 4; ++t) {
                float4v sA = __builtin_amdgcn_mfma_f32_16x16x32_bf16(a3lA, b3f[t * 2],     z0, 0, 0, 0);
                sA         = __builtin_amdgcn_mfma_f32_16x16x32_bf16(a3hA, b3f[t * 2 + 1], sA, 0, 0, 0);
                float4v sB = __builtin_amdgcn_mfma_f32_16x16x32_bf16(a3lB, b3f[t * 2],     z0, 0, 0, 0);
                sB         = __builtin_amdgcn_mfma_f32_16x16x32_bf16(a3hB, b3f[t * 2 + 1], sB, 0, 0, 0);
                float e0A = fexp2(sA[0]), e1A = fexp2(sA[1]);
                float e2A = fexp2(sA[2]), e3A = fexp2(sA[3]);
                float e0B = fexp2(sB[0]), e1B = fexp2(sB[1]);
                float e2B = fexp2(sB[2]), e3B = fexp2(sB[3]);
                seA[t] = (e0A + e1A) + (e2A + e3A);
                snA[t] = fmaf(e0A, xrA[t][0], e1A * xrA[t][1]) + fmaf(e2A, xrA[t][2], e3A * xrA[t][3]);
                seB[t] = (e0B + e1B) + (e2B + e3B);
                snB[t] = fmaf(e0B, xrB[t][0], e1B * xrB[t][1]) + fmaf(e2B, xrB[t][2], e3B * xrB[t][3]);
            }
            #pragma unroll
            for (int t = 0; t < 4; ++t) {
                seA[t] += __shfl_xor(seA[t], 16, 64);
                snA[t] += __shfl_xor(snA[t], 16, 64);
                seB[t] += __shfl_xor(seB[t], 16, 64);
                snB[t] += __shfl_xor(snB[t], 16, 64);
                seA[t] += __shfl_xor(seA[t], 32, 64);
                snA[t] += __shfl_xor(snA[t], 32, 64);
                seB[t] += __shfl_xor(seB[t], 32, 64);
                snB[t] += __shfl_xor(snB[t], 32, 64);
            }
            // all-lane tail: lane handles t=Q, channel 16Q+r -> PL pos 4r+Q
            {
                const float snqA = (Q == 0) ? snA[0] : (Q == 1) ? snA[1] : (Q == 2) ? snA[2] : snA[3];
                const float seqA = (Q == 0) ? seA[0] : (Q == 1) ? seA[1] : (Q == 2) ? seA[2] : seA[3];
                const float snqB = (Q == 0) ? snB[0] : (Q == 1) ? snB[1] : (Q == 2) ? snB[2] : snB[3];
                const float seqB = (Q == 0) ? seB[0] : (Q == 1) ? seB[1] : (Q == 2) ? seB[2] : seB[3];
                sPL[(4 * it + 2 * pp) * 72 + 4 * r + Q]     = f2bf(__fdividef(snqA, seqA));
                sPL[(4 * it + 2 * pp + 1) * 72 + 4 * r + Q] = f2bf(__fdividef(snqB, seqB));
            }
        }
        __builtin_amdgcn_s_setprio(0);
    }

    // ===== ONE pool MFMA epilogue for all 16 block points (all lanes valid) =====
    short8v pbf[8];
    #pragma unroll
    for (int i = 0; i < 8; ++i) pbf[i] = FR[(14 + i) * 64 + l];
    float spv[4], tpv[4];
    #pragma unroll
    for (int t = 0; t < 4; ++t) {
        spv[t] = SC[(12 + t) * 64 + l]; tpv[t] = SC[(16 + t) * 64 + l];
    }
    const short8v apl0 = *(const short8v*)&sPL[r * 72 + Q * 8];
    const short8v apl1 = *(const short8v*)&sPL[r * 72 + 32 + Q * 8];
    float4v dp[4];
    #pragma unroll
    for (int t = 0; t < 4; ++t) {
        float4v d = __builtin_amdgcn_mfma_f32_16x16x32_bf16(apl0, pbf[t * 2],     z0, 0, 0, 0);
        d         = __builtin_amdgcn_mfma_f32_16x16x32_bf16(apl1, pbf[t * 2 + 1], d,  0, 0, 0);
        dp[t] = d;
    }
    // D: row = 4Q+q = block point, col = 16t+r = output channel -> dense stores
    #pragma unroll
    for (int q = 0; q < 4; ++q)
        #pragma unroll
        for (int t = 0; t < 4; ++t)
            out[(ptb + 4 * Q + q) * 64 + 16 * t + r] =
                fmaxf(fmaf(dp[t][q], spv[t], tpv[t]), 0.f);
}

extern "C" void kernel_launch(void* const* d_in, const int* in_sizes, int n_in,
                              void* d_out, int out_size, void* d_ws, size_t ws_size,
                              hipStream_t stream) {
    (void)in_sizes; (void)n_in; (void)ws_size; (void)out_size;
    const float* coords = (const float*)d_in[0];
    const float* feats  = (const float*)d_in[1];
    const int*   nidx   = (const int*)  d_in[2];
    const float* w1  = (const float*)d_in[3];
    const float* g1  = (const float*)d_in[4];
    const float* b1  = (const float*)d_in[5];
    const float* w2  = (const float*)d_in[6];
    const float* g2  = (const float*)d_in[7];
    const float* b2  = (const float*)d_in[8];
    const float* wm1 = (const float*)d_in[9];
    const float* gm1 = (const float*)d_in[10];
    const float* bm1 = (const float*)d_in[11];
    const float* wm2 = (const float*)d_in[12];
    const float* gm2 = (const float*)d_in[13];
    const float* bm2 = (const float*)d_in[14];
    const float* watt = (const float*)d_in[15];
    const float* wp  = (const float*)d_in[16];
    const float* gp  = (const float*)d_in[17];
    const float* bp  = (const float*)d_in[18];
    float* out = (float*)d_out;
    ushort* ws = (ushort*)d_ws;

    lfa_pack<<<dim3(12), dim3(256), 0, stream>>>(wm1, wm2, watt, wp,
                                                 gm1, bm1, gm2, bm2, gp, bp,
                                                 w2, g2, b2, ws);
    lfa_kernel<<<dim3(4096), dim3(64), 0, stream>>>(coords, feats, nidx,
                                                    w1, g1, b1, ws, out);
}